// Round 8
// baseline (96.326 us; speedup 1.0000x reference)
//
#include <hip/hip_runtime.h>

// Problem constants (match reference)
static constexpr int CB = 2;
static constexpr int CN = 256;
static constexpr int CK = 16;
static constexpr int NBLK = CB * CN;          // 512 blocks, 2/CU -> co-resident
static constexpr int NTRI = 136;              // K*(K+1)/2
#define F_ALPHA 0.01f
#define F_LAM   1.0f
#define F_KAPPA 1.0f
#define F_EPS   1e-6f
#define F_GCLIP 1000.0f

// triangle row offset: TRI(r) = r*(33-r)/2
#define TRIOFF(r) ((r)*(33-(r))/2)

// ---------------------------------------------------------------------------
// Fused kernel (R7 structure). Barrier protocol fixed:
//   - arrival: one release fence (__threadfence) + RELAXED fetch_add
//   - poll:    RELAXED agent-scope load (performed at coherence point, but
//              NO per-poll cache invalidate — this was R7's 70us storm)
//   - exit:    one acquire-side __threadfence (L2 inv) for cross-XCD data
// ---------------------------------------------------------------------------
__global__ __launch_bounds__(256, 2) void vfe_fused_kernel(
    const float* __restrict__ mu_q, const float* __restrict__ sigma_q,
    const float* __restrict__ mu_p, const float* __restrict__ sigma_p,
    const float* __restrict__ beta, const float* __restrict__ phi,
    const float* __restrict__ gens, const float* __restrict__ lr,
    float* __restrict__ wsWtri, float* __restrict__ wsUT,
    unsigned* __restrict__ cnt, float* __restrict__ out)
{
    const int bn = blockIdx.x;          // node (b,n) == output row (b,i)
    const int b  = bn >> 8;
    const int n  = bn & 255;
    const int t  = threadIdx.x;         // phase1: element (r,c); phase2: j
    const int r  = t >> 4;
    const int c  = t & 15;

    // phase-1 scratch
    __shared__ float Ms[256];
    __shared__ float Pa[256], Pb[256];
    __shared__ float Ta[256], Tb[256];  // Ta ends as R, persists into phase 2
    __shared__ float Wst[256];
    __shared__ float msh[CK], dinv[CK];
    __shared__ float uish[CK];          // u_i, persists
    // phase-2 scratch
    __shared__ float Hs[256][17];
    __shared__ float bets[256];
    __shared__ float bkls[256];
    __shared__ float partS1[4][16];
    __shared__ float partS2[4][16];
    __shared__ float partS3[4];
    __shared__ float grot[CK];

    // ================= Phase 1: prep =================
    const float p0 = phi[bn*3+0];
    const float p1 = phi[bn*3+1];
    const float p2 = phi[bn*3+2];

    const float diag = (r == c) ? 1.0f : 0.0f;
    float m = p0*gens[t] + p1*gens[256+t] + p2*gens[512+t];
    m *= (1.0f/16.0f);
    Ms[t] = m;
    Pa[t] = m;
    if (t < CK) {
        msh[t]  = mu_q[bn*CK + t];
        dinv[t] = 1.0f / (fmaxf(sigma_q[bn*CK + t], F_EPS) + F_EPS);
    }
    __syncthreads();

    float mscol[CK];
    #pragma unroll
    for (int l = 0; l < CK; ++l) mscol[l] = Ms[l*CK + c];

    float Treg = diag + m;
    #pragma unroll
    for (int k = 2; k <= 8; ++k) {                 // Taylor, ping-pong
        const float* Pc = (k & 1) ? Pb : Pa;
        float*       Pn = (k & 1) ? Pa : Pb;
        float acc = 0.f;
        #pragma unroll
        for (int l = 0; l < CK; ++l) acc += Pc[r*CK+l] * mscol[l];
        acc *= (1.0f / (float)k);
        Pn[t] = acc;
        Treg += acc;
        __syncthreads();
    }

    Ta[t] = Treg;
    __syncthreads();
    #pragma unroll
    for (int s = 0; s < 4; ++s) {                  // 4 squarings; final in Ta
        const float* Tc = (s & 1) ? Tb : Ta;
        float*       Tn = (s & 1) ? Ta : Tb;
        float acc = 0.f;
        #pragma unroll
        for (int l = 0; l < CK; ++l) acc += Tc[r*CK+l] * Tc[l*CK+c];
        Tn[t] = acc;
        __syncthreads();
    }
    // Ta = R

    // u = R^T mu -> global (transposed over n) + LDS copy
    if (t < CK) {
        float acc = 0.f;
        #pragma unroll
        for (int l = 0; l < CK; ++l) acc += Ta[l*CK+t] * msh[l];
        wsUT[(b*CK + t)*CN + n] = acc;
        uish[t] = acc;
    }

    // W element (r,c)
    {
        float acc = 0.f;
        #pragma unroll
        for (int l = 0; l < CK; ++l) acc += Ta[l*CK+r] * dinv[l] * Ta[l*CK+c];
        Wst[t] = acc;
    }
    __syncthreads();

    // upper-triangle store: thread e<136 -> (re,ce), write [b][e][n]
    if (t < NTRI) {
        int re = 0;
        #pragma unroll
        for (int q = 1; q < 16; ++q) re += (t >= TRIOFF(q));
        const int ce = t - TRIOFF(re) + re;
        wsWtri[(b*NTRI + t)*CN + n] = Wst[re*CK + ce];
    }

    // ================= Grid barrier (fixed protocol) =================
    __threadfence();          // release: writeback this XCD's L2 (once/block)
    __syncthreads();
    if (t == 0) {
        __hip_atomic_fetch_add(cnt, 1u, __ATOMIC_RELAXED, __HIP_MEMORY_SCOPE_AGENT);
        while (__hip_atomic_load(cnt, __ATOMIC_RELAXED, __HIP_MEMORY_SCOPE_AGENT)
               < (unsigned)NBLK) {
            __builtin_amdgcn_s_sleep(8);
        }
        __threadfence();      // acquire side: invalidate so cross-XCD data visible
    }
    __syncthreads();

    // ================= Phase 2: pair (i = n, thread = j = t) ============
    const float* uTb = wsUT + b*CK*CN;
    float d[CK];
    #pragma unroll
    for (int cc = 0; cc < CK; ++cc) d[cc] = uish[cc] - uTb[cc*CN + t];

    // h = W_j d via symmetric triangle (lane-coalesced b32 loads)
    const float* Wt = wsWtri + (size_t)b*NTRI*CN + t;
    float h[CK];
    #pragma unroll
    for (int q = 0; q < CK; ++q) h[q] = 0.f;
    {
        int e = 0;
        #pragma unroll
        for (int rr = 0; rr < CK; ++rr) {
            #pragma unroll
            for (int cc = rr; cc < CK; ++cc) {
                const float w = Wt[e*CN];
                h[rr] += w * d[cc];
                if (cc > rr) h[cc] += w * d[rr];
                ++e;
            }
        }
    }
    float kl = 0.f;
    #pragma unroll
    for (int q = 0; q < CK; ++q) { Hs[t][q] = h[q]; kl += h[q]*d[q]; }
    kl *= 0.5f;

    const float bt = beta[(b*CN + n)*CN + t];
    bets[t] = bt;
    bkls[t] = bt * kl;
    __syncthreads();

    // Phase B reduction: thread = (jg = t>>4, k = t&15)
    {
        const int k  = t & 15;
        const int jg = t >> 4;
        float s1p = 0.f, s2p = 0.f, s3p = 0.f;
        #pragma unroll
        for (int s = 0; s < 16; ++s) {
            const int jj = jg*16 + s;
            const float hv = Hs[jj][k];
            const float be = bets[jj];
            const float bk = bkls[jj];
            s1p += be * hv;
            s2p += bk * hv;
            s3p += bk;
        }
        s1p += __shfl_down(s1p, 16);  s1p += __shfl_down(s1p, 32);
        s2p += __shfl_down(s2p, 16);  s2p += __shfl_down(s2p, 32);
        s3p += __shfl_down(s3p, 16);  s3p += __shfl_down(s3p, 32);

        const int lane = t & 63;
        const int wv   = t >> 6;
        if (lane < 16) {
            partS1[wv][lane] = s1p;
            partS2[wv][lane] = s2p;
            if (lane == 0) partS3[wv] = s3p;
        }
    }
    __syncthreads();

    if (t < CK) {
        const float s1 = partS1[0][t] + partS1[1][t] + partS1[2][t] + partS1[3][t];
        const float s2 = partS2[0][t] + partS2[1][t] + partS2[2][t] + partS2[3][t];
        const float s3 = partS3[0] + partS3[1] + partS3[2] + partS3[3];
        grot[t] = F_LAM*s1 + (F_LAM/F_KAPPA)*(s2 - s3*s1);
    }
    __syncthreads();

    // Epilogue: R is LDS-resident (Ta)
    if (t < CK) {
        const int rr = t;
        float acc = 0.f;
        #pragma unroll
        for (int cc = 0; cc < CK; ++cc) acc += Ta[rr*CK+cc] * grot[cc];

        const int idx = bn*CK + rr;
        const float mq = mu_q[idx];
        const float sq = sigma_q[idx];
        const float mp = mu_p[idx];
        const float sp = sigma_p[idx];
        const float sps = fmaxf(sp, F_EPS);
        const float sqs = fmaxf(sq, F_EPS);

        const float gmu = F_ALPHA*(mq - mp)/sps + acc;
        const float gsg = F_ALPHA*0.5f*(1.0f/sps - 1.0f/sqs);

        float nmu = sqs * gmu;
        float nsg = 0.5f * sqs * sqs * gsg;
        nmu = fminf(fmaxf(nmu, -F_GCLIP), F_GCLIP);
        nsg = fminf(fmaxf(nsg, -F_GCLIP), F_GCLIP);

        const float step = lr[0];
        out[idx]             = mq - step*nmu;                 // mu_new
        out[CB*CN*CK + idx]  = fmaxf(sq - step*nsg, F_EPS);   // sigma_new
    }
}

extern "C" void kernel_launch(void* const* d_in, const int* in_sizes, int n_in,
                              void* d_out, int out_size, void* d_ws, size_t ws_size,
                              hipStream_t stream) {
    const float* mu_q    = (const float*)d_in[0];
    const float* sigma_q = (const float*)d_in[1];
    const float* mu_p    = (const float*)d_in[2];
    const float* sigma_p = (const float*)d_in[3];
    const float* beta    = (const float*)d_in[4];
    const float* phi     = (const float*)d_in[5];
    const float* gens    = (const float*)d_in[6];
    const float* lr      = (const float*)d_in[7];
    float* out = (float*)d_out;

    float*    wsWtri = (float*)d_ws;                  // [b][e<136][n]  69632 floats
    float*    wsUT   = wsWtri + CB*NTRI*CN;           // [b][c][n]       8192 floats
    unsigned* cnt    = (unsigned*)(wsUT + CB*CK*CN);  // barrier counter

    hipMemsetAsync(cnt, 0, sizeof(unsigned), stream);
    vfe_fused_kernel<<<NBLK, 256, 0, stream>>>(mu_q, sigma_q, mu_p, sigma_p,
                                               beta, phi, gens, lr,
                                               wsWtri, wsUT, cnt, out);
}

// Round 9
// 16.369 us; speedup vs baseline: 5.8845x; 5.8845x over previous
//
#include <hip/hip_runtime.h>

// Problem constants (match reference)
static constexpr int CB = 2;
static constexpr int CN = 256;
static constexpr int CK = 16;
static constexpr int NTRI = 136;              // K*(K+1)/2
#define F_ALPHA 0.01f
#define F_LAM   1.0f
#define F_KAPPA 1.0f
#define F_EPS   1e-6f
#define F_GCLIP 1000.0f

// triangle row offset: TRI(r) = r*(33-r)/2
#define TRIOFF(r) ((r)*(33-(r))/2)

// ---------------------------------------------------------------------------
// Kernel 1: per (b,n):
//   R = expm(sum_a phi_a G_a)  (orthogonal; scale 1/16 + 8-term Taylor + 4 sq)
//   u = R^T mu_q                   -> wsUT[b][c][n]
//   W = R^T diag(1/(sig+eps)) R    (symmetric) -> upper tri wsWtri[b][e][n]
//   R -> wsR[b][n][16][16] (epilogue use in kernel 2)
// ---------------------------------------------------------------------------
__global__ __launch_bounds__(256) void vfe_prep_kernel(
    const float* __restrict__ mu_q, const float* __restrict__ sigma_q,
    const float* __restrict__ phi, const float* __restrict__ gens,
    float* __restrict__ wsR, float* __restrict__ wsWtri, float* __restrict__ wsUT)
{
    const int bn = blockIdx.x;          // 0 .. B*N-1
    const int b  = bn >> 8;
    const int n  = bn & 255;
    const int t  = threadIdx.x;         // element (r,c)
    const int r  = t >> 4;
    const int c  = t & 15;

    __shared__ float Ms[256];
    __shared__ float Pa[256], Pb[256];
    __shared__ float Ta[256], Tb[256];
    __shared__ float Wst[256];
    __shared__ float msh[CK], dinv[CK];

    const float p0 = phi[bn*3+0];
    const float p1 = phi[bn*3+1];
    const float p2 = phi[bn*3+2];

    const float diag = (r == c) ? 1.0f : 0.0f;
    float m = p0*gens[t] + p1*gens[256+t] + p2*gens[512+t];
    m *= (1.0f/16.0f);                  // 4 squarings later
    Ms[t] = m;
    Pa[t] = m;
    if (t < CK) {
        msh[t]  = mu_q[bn*CK + t];
        dinv[t] = 1.0f / (fmaxf(sigma_q[bn*CK + t], F_EPS) + F_EPS);
    }
    __syncthreads();

    // cache column c of Ms in registers
    float mscol[CK];
    #pragma unroll
    for (int l = 0; l < CK; ++l) mscol[l] = Ms[l*CK + c];

    float Treg = diag + m;
    // Taylor k=2..8, ping-pong Pa/Pb, 1 barrier/iter
    #pragma unroll
    for (int k = 2; k <= 8; ++k) {
        const float* Pc = (k & 1) ? Pb : Pa;
        float*       Pn = (k & 1) ? Pa : Pb;
        float acc = 0.f;
        #pragma unroll
        for (int l = 0; l < CK; ++l) acc += Pc[r*CK+l] * mscol[l];
        acc *= (1.0f / (float)k);
        Pn[t] = acc;
        Treg += acc;
        __syncthreads();
    }

    // 4 squarings, ping-pong Ta/Tb; final lands in Ta
    Ta[t] = Treg;
    __syncthreads();
    #pragma unroll
    for (int s = 0; s < 4; ++s) {
        const float* Tc = (s & 1) ? Tb : Ta;
        float*       Tn = (s & 1) ? Ta : Tb;
        float acc = 0.f;
        #pragma unroll
        for (int l = 0; l < CK; ++l) acc += Tc[r*CK+l] * Tc[l*CK+c];
        Tn[t] = acc;
        __syncthreads();
    }
    // Ta = R (all lanes synced)

    // u = R^T mu (threads 0..15)
    if (t < CK) {
        float acc = 0.f;
        #pragma unroll
        for (int l = 0; l < CK; ++l) acc += Ta[l*CK+t] * msh[l];
        wsUT[(b*CK + t)*CN + n] = acc;
    }

    // R store: threads 64..127 write float4 chunks from Ta
    if (t >= 64 && t < 128) {
        const int g = t - 64;
        float4 v;
        v.x = Ta[4*g+0]; v.y = Ta[4*g+1]; v.z = Ta[4*g+2]; v.w = Ta[4*g+3];
        ((float4*)wsR)[bn*64 + g] = v;
    }

    // W element (r,c) -> Wst
    {
        float acc = 0.f;
        #pragma unroll
        for (int l = 0; l < CK; ++l) acc += Ta[l*CK+r] * dinv[l] * Ta[l*CK+c];
        Wst[t] = acc;
    }
    __syncthreads();

    // upper-triangle store: thread e<136 -> (re,ce), write [b][e][n]
    if (t < NTRI) {
        int re = 0;
        #pragma unroll
        for (int q = 1; q < 16; ++q) re += (t >= TRIOFF(q));
        const int ce = t - TRIOFF(re) + re;
        wsWtri[(b*NTRI + t)*CN + n] = Wst[re*CK + ce];
    }
}

// ---------------------------------------------------------------------------
// Kernel 2 (R6 structure; W reads via symmetric triangle):
//   Phase A (thread=j): d = u_i - u_j; h = W_j d (tri: each elem feeds h[r],
//                       h[c]); kl = 0.5 d.h; H[j][k]->LDS, beta/beta*kl->LDS
//   Phase B (thread=(jg,k)): partial dots over 16 j's, 2-step wave shuffle
//   Phase C + epilogue (thread=k<16)
// ---------------------------------------------------------------------------
__global__ __launch_bounds__(256) void vfe_pair_kernel(
    const float* __restrict__ mu_q, const float* __restrict__ sigma_q,
    const float* __restrict__ mu_p, const float* __restrict__ sigma_p,
    const float* __restrict__ beta, const float* __restrict__ lr,
    const float* __restrict__ wsR, const float* __restrict__ wsWtri,
    const float* __restrict__ wsUT, float* __restrict__ out)
{
    const int bi = blockIdx.x;      // b*N + i
    const int b  = bi >> 8;
    const int i  = bi & 255;
    const int t  = threadIdx.x;     // 0..255 (= j in phase A)

    __shared__ float uish[CK];
    __shared__ float Hs[256][17];
    __shared__ float bets[256];
    __shared__ float bkls[256];
    __shared__ float partS1[4][16];
    __shared__ float partS2[4][16];
    __shared__ float partS3[4];
    __shared__ float grot[CK];

    if (t < CK) uish[t] = wsUT[(b*CK + t)*CN + i];
    __syncthreads();

    // ---- Phase A ----
    const float* uTb = wsUT + b*CK*CN;
    float d[CK];
    #pragma unroll
    for (int cc = 0; cc < CK; ++cc) d[cc] = uish[cc] - uTb[cc*CN + t];

    // h = W_j d via symmetric triangle (lane-coalesced b32 loads)
    const float* Wt = wsWtri + (size_t)b*NTRI*CN + t;
    float h[CK];
    #pragma unroll
    for (int q = 0; q < CK; ++q) h[q] = 0.f;
    {
        int e = 0;
        #pragma unroll
        for (int rr = 0; rr < CK; ++rr) {
            #pragma unroll
            for (int cc = rr; cc < CK; ++cc) {
                const float w = Wt[e*CN];
                h[rr] += w * d[cc];
                if (cc > rr) h[cc] += w * d[rr];
                ++e;
            }
        }
    }
    float kl = 0.f;
    #pragma unroll
    for (int q = 0; q < CK; ++q) { Hs[t][q] = h[q]; kl += h[q]*d[q]; }
    kl *= 0.5f;

    const float bt = beta[(b*CN + i)*CN + t];
    bets[t] = bt;
    bkls[t] = bt * kl;
    __syncthreads();

    // ---- Phase B: thread = (jg = t>>4, k = t&15) ----
    {
        const int k  = t & 15;
        const int jg = t >> 4;
        float s1p = 0.f, s2p = 0.f, s3p = 0.f;
        #pragma unroll
        for (int s = 0; s < 16; ++s) {
            const int jj = jg*16 + s;
            const float hv = Hs[jj][k];
            const float be = bets[jj];
            const float bk = bkls[jj];
            s1p += be * hv;
            s2p += bk * hv;
            s3p += bk;
        }
        s1p += __shfl_down(s1p, 16);  s1p += __shfl_down(s1p, 32);
        s2p += __shfl_down(s2p, 16);  s2p += __shfl_down(s2p, 32);
        s3p += __shfl_down(s3p, 16);  s3p += __shfl_down(s3p, 32);

        const int lane = t & 63;
        const int wv   = t >> 6;
        if (lane < 16) {
            partS1[wv][lane] = s1p;
            partS2[wv][lane] = s2p;
            if (lane == 0) partS3[wv] = s3p;
        }
    }
    __syncthreads();

    // ---- Phase C ----
    if (t < CK) {
        const float s1 = partS1[0][t] + partS1[1][t] + partS1[2][t] + partS1[3][t];
        const float s2 = partS2[0][t] + partS2[1][t] + partS2[2][t] + partS2[3][t];
        const float s3 = partS3[0] + partS3[1] + partS3[2] + partS3[3];
        grot[t] = F_LAM*s1 + (F_LAM/F_KAPPA)*(s2 - s3*s1);
    }
    __syncthreads();

    // ---- Epilogue ----
    if (t < CK) {
        const int rr = t;
        const float* Ri = wsR + bi*256;
        float acc = 0.f;
        #pragma unroll
        for (int cc = 0; cc < CK; ++cc) acc += Ri[rr*CK+cc] * grot[cc];

        const int idx = bi*CK + rr;
        const float mq = mu_q[idx];
        const float sq = sigma_q[idx];
        const float mp = mu_p[idx];
        const float sp = sigma_p[idx];
        const float sps = fmaxf(sp, F_EPS);
        const float sqs = fmaxf(sq, F_EPS);

        const float gmu = F_ALPHA*(mq - mp)/sps + acc;
        const float gsg = F_ALPHA*0.5f*(1.0f/sps - 1.0f/sqs);

        float nmu = sqs * gmu;
        float nsg = 0.5f * sqs * sqs * gsg;
        nmu = fminf(fmaxf(nmu, -F_GCLIP), F_GCLIP);
        nsg = fminf(fmaxf(nsg, -F_GCLIP), F_GCLIP);

        const float step = lr[0];
        out[idx]             = mq - step*nmu;                 // mu_new
        out[CB*CN*CK + idx]  = fmaxf(sq - step*nsg, F_EPS);   // sigma_new
    }
}

extern "C" void kernel_launch(void* const* d_in, const int* in_sizes, int n_in,
                              void* d_out, int out_size, void* d_ws, size_t ws_size,
                              hipStream_t stream) {
    const float* mu_q    = (const float*)d_in[0];
    const float* sigma_q = (const float*)d_in[1];
    const float* mu_p    = (const float*)d_in[2];
    const float* sigma_p = (const float*)d_in[3];
    const float* beta    = (const float*)d_in[4];
    const float* phi     = (const float*)d_in[5];
    const float* gens    = (const float*)d_in[6];
    const float* lr      = (const float*)d_in[7];
    float* out = (float*)d_out;

    float* wsR    = (float*)d_ws;               // [b][n][16][16]
    float* wsWtri = wsR + CB*CN*CK*CK;          // [b][e<136][n]
    float* wsUT   = wsWtri + CB*NTRI*CN;        // [b][c][n]

    vfe_prep_kernel<<<CB*CN, 256, 0, stream>>>(mu_q, sigma_q, phi, gens,
                                               wsR, wsWtri, wsUT);
    vfe_pair_kernel<<<CB*CN, 256, 0, stream>>>(mu_q, sigma_q, mu_p, sigma_p, beta, lr,
                                               wsR, wsWtri, wsUT, out);
}